// Round 1
// baseline (18071.043 us; speedup 1.0000x reference)
//
#include <hip/hip_runtime.h>

// Problem dims
#define BATCH 256
#define TLEN  512
#define DIN   128
#define DFEAT 256
#define DLAT  512
#define G4    2048   // 4*DLAT
#define KCAT  768    // DFEAT + DLAT

typedef __bf16 bf16x8 __attribute__((ext_vector_type(8)));
typedef float f32x4 __attribute__((ext_vector_type(4)));

// ws layout (bytes)
#define WCAT_OFF   0u           // 768x2048 bf16 frag-linear: 3,145,728
#define WENC_OFF   3145728u    // 128x256  bf16 frag-linear: 65,536
#define ENC_OFF    3211264u    // enc bf16 [T][B][256]: 67,108,864
#define H_OFF      70320128u   // h dbuf bf16 [2][256][512]: 524,288
#define FLAG_OFF   70844416u   // 8 grp x 32 wg x 64B: 16,384

__device__ __forceinline__ float sigf(float x)  { return 1.0f / (1.0f + __expf(-x)); }
__device__ __forceinline__ float tanhfast(float x){ return 2.0f / (1.0f + __expf(-2.0f * x)) - 1.0f; }
__device__ __forceinline__ unsigned short bfb(float f) {
    __bf16 b = (__bf16)f;
    return __builtin_bit_cast(unsigned short, b);
}

// ---------------------------------------------------------------------------
// Weight prep: build bf16 fragment-linear copies of [W_x;W_h] (768x2048) and
// W_enc (128x256). Fragment chunk = 16B for one lane of one 16x16x32 B-frag:
// B[k = ks*32 + (l>>4)*8 + j][col], col = (l&15) within a 16-col Ntile.
// ---------------------------------------------------------------------------
__global__ __launch_bounds__(256) void wprep_kernel(const float* __restrict__ Wx,
                                                    const float* __restrict__ Wh,
                                                    const float* __restrict__ Wenc,
                                                    __bf16* __restrict__ wcat,
                                                    __bf16* __restrict__ wencf) {
    int cid = blockIdx.x * 256 + threadIdx.x;   // 200704 total
    float v[8];
    __bf16* dst;
    if (cid < 196608) {
        // Wcat: cid = ((widx*4 + nt)*24 + ks)*64 + l
        int widx = cid / 6144;
        int r1 = cid % 6144;
        int nt = r1 / 1536;
        int r2 = r1 % 1536;
        int ks = r2 >> 6, l = r2 & 63;
        int col = nt * 512 + widx * 16 + (l & 15);
        int kc = ks * 32 + (l >> 4) * 8;
#pragma unroll
        for (int j = 0; j < 8; ++j) {
            int kk = kc + j;
            v[j] = (kk < DFEAT) ? Wx[kk * G4 + col] : Wh[(kk - DFEAT) * G4 + col];
        }
        dst = wcat + (size_t)cid * 8;
    } else {
        // Wenc: c2 = ((ntg*4 + ks)*64 + l)
        int c2 = cid - 196608;   // [0, 4096)
        int ntg = c2 >> 8;
        int r = c2 & 255;
        int ks = r >> 6, l = r & 63;
        int col = ntg * 16 + (l & 15);
        int kc = ks * 32 + (l >> 4) * 8;
#pragma unroll
        for (int j = 0; j < 8; ++j) v[j] = Wenc[(kc + j) * DFEAT + col];
        dst = wencf + (size_t)c2 * 8;
    }
    bf16x8 o;
#pragma unroll
    for (int j = 0; j < 8; ++j) o[j] = (__bf16)v[j];
    *reinterpret_cast<bf16x8*>(dst) = o;
}

// ---------------------------------------------------------------------------
// Encoder: enc[t][b][f] = tanh(x[b][t][:] @ W_enc + b_enc), bf16 out.
// Block: 64 rows (rid = b*512+t) x 64 cols. 4 waves, wave = 1 Mtile x 4 Ntiles.
// ---------------------------------------------------------------------------
__global__ __launch_bounds__(256) void enc_kernel(const float* __restrict__ x,
                                                  const float* __restrict__ benc,
                                                  const __bf16* __restrict__ wencf,
                                                  __bf16* __restrict__ enc) {
    __shared__ uint4 afrag4[1024];   // 16 KB frag-linear A: [(m*4+ks)*64 + l]
    __bf16* afrag = reinterpret_cast<__bf16*>(afrag4);
    int tid = threadIdx.x;
    int lane = tid & 63, w = tid >> 6;
    int rid0 = blockIdx.x * 64;
    int ntg0 = blockIdx.y * 4;

    bf16x8 wr[4][4];
#pragma unroll
    for (int n = 0; n < 4; ++n)
#pragma unroll
        for (int ks = 0; ks < 4; ++ks)
            wr[n][ks] = *reinterpret_cast<const bf16x8*>(
                wencf + (size_t)(((ntg0 + n) * 4 + ks) * 64 + lane) * 8);
    float bias[4];
#pragma unroll
    for (int n = 0; n < 4; ++n) bias[n] = benc[(ntg0 + n) * 16 + (lane & 15)];

    // stage x tile (64 rows x 128 k) as bf16 frags
#pragma unroll
    for (int i = 0; i < 4; ++i) {
        int c = tid + 256 * i;          // [0,1024): row = c>>4, k8 = c&15
        int row = c >> 4, k8 = c & 15;
        const float* src = x + (size_t)(rid0 + row) * DIN + k8 * 8;
        float4 f0 = *reinterpret_cast<const float4*>(src);
        float4 f1 = *reinterpret_cast<const float4*>(src + 4);
        bf16x8 o;
        o[0] = (__bf16)f0.x; o[1] = (__bf16)f0.y; o[2] = (__bf16)f0.z; o[3] = (__bf16)f0.w;
        o[4] = (__bf16)f1.x; o[5] = (__bf16)f1.y; o[6] = (__bf16)f1.z; o[7] = (__bf16)f1.w;
        int l = (k8 & 3) * 16 + (row & 15);
        int a16 = ((row >> 4) * 4 + (k8 >> 2)) * 64 + l;
        *reinterpret_cast<bf16x8*>(afrag + (size_t)a16 * 8) = o;
    }
    __syncthreads();

    int m = w;
    f32x4 acc[4];
#pragma unroll
    for (int n = 0; n < 4; ++n) acc[n] = (f32x4){bias[n], bias[n], bias[n], bias[n]};
#pragma unroll
    for (int ks = 0; ks < 4; ++ks) {
        bf16x8 a = *reinterpret_cast<const bf16x8*>(afrag + (size_t)((m * 4 + ks) * 64 + lane) * 8);
#pragma unroll
        for (int n = 0; n < 4; ++n)
            acc[n] = __builtin_amdgcn_mfma_f32_16x16x32_bf16(a, wr[n][ks], acc[n], 0, 0, 0);
    }
#pragma unroll
    for (int n = 0; n < 4; ++n) {
        int colg = (ntg0 + n) * 16 + (lane & 15);
#pragma unroll
        for (int q = 0; q < 4; ++q) {
            int rid = rid0 + m * 16 + (lane >> 4) * 4 + q;
            int bb = rid >> 9, tt = rid & 511;
            float th = tanhfast(acc[n][q]);
            enc[(size_t)(tt * BATCH + bb) * DFEAT + colg] = (__bf16)th;
        }
    }
}

// ---------------------------------------------------------------------------
// Persistent LSTM. grid=256 (grp = bid&7 -> 32 batch rows; widx = bid>>3 ->
// 16 k-cols = 64 gate-cols). Weights in VGPRs (48 frags). A = [enc_t | h] in
// fragment-linear LDS. Group barrier via per-wg flags in global memory.
// ---------------------------------------------------------------------------
__global__ __launch_bounds__(256, 1) void lstm_kernel(const __bf16* __restrict__ enc,
                                                      const __bf16* __restrict__ wcat,
                                                      const float* __restrict__ blstm,
                                                      __bf16* __restrict__ hbuf,
                                                      unsigned int* __restrict__ flags) {
    extern __shared__ char smem[];
    __bf16* afrag = reinterpret_cast<__bf16*>(smem);        // 49152 B
    float* zbuf = reinterpret_cast<float*>(smem + 49152);   // 8192 B: [4][32][16]

    int tid = threadIdx.x;
    int lane = tid & 63, w = tid >> 6;
    int m = w & 1, np = w >> 1;
    int grp = blockIdx.x & 7, widx = blockIdx.x >> 3;
    int b0 = grp * 32;

    // persistent weight frags
    bf16x8 wreg[2][24];
#pragma unroll
    for (int n2 = 0; n2 < 2; ++n2)
#pragma unroll
        for (int ks = 0; ks < 24; ++ks)
            wreg[n2][ks] = *reinterpret_cast<const bf16x8*>(
                wcat + (size_t)(((widx * 4 + np * 2 + n2) * 24 + ks) * 64 + lane) * 8);
    float bias[2];
#pragma unroll
    for (int n2 = 0; n2 < 2; ++n2)
        bias[n2] = blstm[(np * 2 + n2) * DLAT + widx * 16 + (lane & 15)];

    // cell state: thread owns cells 2*tid, 2*tid+1 of the wg's 32x16 slice
    int cell = 2 * tid;
    int crow = cell >> 4, ckk = cell & 15;
    float c0 = 0.f, c1 = 0.f;
    unsigned int* myflag = flags + (grp * 32 + widx) * 16;

#pragma unroll 1
    for (int t = 0; t < TLEN; ++t) {
        if (t > 0) {
            if (tid < 32) {
                const unsigned int* f = flags + (grp * 32 + tid) * 16;
                while (__hip_atomic_load(f, __ATOMIC_ACQUIRE, __HIP_MEMORY_SCOPE_AGENT) <
                       (unsigned)t) {}
            }
            __syncthreads();
            __builtin_amdgcn_fence(__ATOMIC_ACQUIRE, "agent");
        }
        // stage A = [enc_t | h(t)] : 32 rows x 768 k, frag-linear
        const __bf16* hsrc = hbuf + (size_t)(t & 1) * (BATCH * DLAT);
#pragma unroll
        for (int i = 0; i < 12; ++i) {
            int c = tid + 256 * i;              // [0,3072)
            int mm = (c >= 1536) ? 1 : 0;
            int r = c - mm * 1536;
            int ks = r >> 6, l = r & 63;
            int row = mm * 16 + (l & 15);
            int k = (ks * 4 + (l >> 4)) * 8;
            const __bf16* src = (k < DFEAT)
                ? enc + (size_t)(t * BATCH + b0 + row) * DFEAT + k
                : hsrc + (size_t)(b0 + row) * DLAT + (k - DFEAT);
            uint4 d = *reinterpret_cast<const uint4*>(src);
            *reinterpret_cast<uint4*>(afrag + (size_t)c * 8) = d;
        }
        __syncthreads();

        // z = A @ Wslice (+bias)
        f32x4 acc[2];
        acc[0] = (f32x4){bias[0], bias[0], bias[0], bias[0]};
        acc[1] = (f32x4){bias[1], bias[1], bias[1], bias[1]};
#pragma unroll
        for (int ks = 0; ks < 24; ++ks) {
            bf16x8 a = *reinterpret_cast<const bf16x8*>(
                afrag + (size_t)((m * 24 + ks) * 64 + lane) * 8);
            acc[0] = __builtin_amdgcn_mfma_f32_16x16x32_bf16(a, wreg[0][ks], acc[0], 0, 0, 0);
            acc[1] = __builtin_amdgcn_mfma_f32_16x16x32_bf16(a, wreg[1][ks], acc[1], 0, 0, 0);
        }
        // z exchange: zbuf[g][rowInWg][kk]
#pragma unroll
        for (int n2 = 0; n2 < 2; ++n2) {
            int g = np * 2 + n2;
#pragma unroll
            for (int q = 0; q < 4; ++q) {
                int rr = m * 16 + (lane >> 4) * 4 + q;
                zbuf[g * 512 + rr * 16 + (lane & 15)] = acc[n2][q];
            }
        }
        __syncthreads();

        // gates + state update (2 cells per thread)
        float2 zi = *reinterpret_cast<float2*>(&zbuf[0 * 512 + cell]);
        float2 zf = *reinterpret_cast<float2*>(&zbuf[1 * 512 + cell]);
        float2 zg = *reinterpret_cast<float2*>(&zbuf[2 * 512 + cell]);
        float2 zo = *reinterpret_cast<float2*>(&zbuf[3 * 512 + cell]);
        float i0 = sigf(zi.x), f0 = sigf(zf.x), g0 = tanhfast(zg.x), o0 = sigf(zo.x);
        c0 = f0 * c0 + i0 * g0;
        float h0 = o0 * tanhfast(c0);
        float i1 = sigf(zi.y), f1 = sigf(zf.y), g1 = tanhfast(zg.y), o1 = sigf(zo.y);
        c1 = f1 * c1 + i1 * g1;
        float h1 = o1 * tanhfast(c1);

        unsigned int hp = (unsigned int)bfb(h0) | ((unsigned int)bfb(h1) << 16);
        __bf16* hdst = hbuf + (size_t)((t + 1) & 1) * (BATCH * DLAT) +
                       (size_t)(b0 + crow) * DLAT + widx * 16 + ckk;
        *reinterpret_cast<unsigned int*>(hdst) = hp;

        __threadfence();
        __syncthreads();
        if (tid == 0)
            __hip_atomic_store(myflag, (unsigned int)(t + 1), __ATOMIC_RELEASE,
                               __HIP_MEMORY_SCOPE_AGENT);
    }
}

// ---------------------------------------------------------------------------
// Decoder: out[b] = h_last[b,:] @ W_dec + b_dec. h_last is hbuf[0] (T even).
// ---------------------------------------------------------------------------
__global__ __launch_bounds__(64) void dec_kernel(const __bf16* __restrict__ hbuf,
                                                 const float* __restrict__ wdec,
                                                 const float* __restrict__ bdec,
                                                 float* __restrict__ out) {
    int b = blockIdx.x, lane = threadIdx.x;
    uint4 d = *reinterpret_cast<const uint4*>(hbuf + (size_t)b * DLAT + lane * 8);
    const __bf16* hv = reinterpret_cast<const __bf16*>(&d);
    float4 w0 = *reinterpret_cast<const float4*>(wdec + lane * 8);
    float4 w1 = *reinterpret_cast<const float4*>(wdec + lane * 8 + 4);
    float s = (float)hv[0] * w0.x + (float)hv[1] * w0.y + (float)hv[2] * w0.z +
              (float)hv[3] * w0.w + (float)hv[4] * w1.x + (float)hv[5] * w1.y +
              (float)hv[6] * w1.z + (float)hv[7] * w1.w;
#pragma unroll
    for (int off = 32; off; off >>= 1) s += __shfl_xor(s, off);
    if (lane == 0) out[b] = s + bdec[0];
}

extern "C" void kernel_launch(void* const* d_in, const int* in_sizes, int n_in,
                              void* d_out, int out_size, void* d_ws, size_t ws_size,
                              hipStream_t stream) {
    (void)in_sizes; (void)n_in; (void)out_size; (void)ws_size;
    const float* x     = (const float*)d_in[0];
    const float* Wenc  = (const float*)d_in[1];
    const float* benc  = (const float*)d_in[2];
    const float* Wx    = (const float*)d_in[3];
    const float* Wh    = (const float*)d_in[4];
    const float* blstm = (const float*)d_in[5];
    const float* Wdec  = (const float*)d_in[6];
    const float* bdec  = (const float*)d_in[7];

    char* ws = (char*)d_ws;
    __bf16* wcat  = (__bf16*)(ws + WCAT_OFF);
    __bf16* wencf = (__bf16*)(ws + WENC_OFF);
    __bf16* enc   = (__bf16*)(ws + ENC_OFF);
    __bf16* hbuf  = (__bf16*)(ws + H_OFF);
    unsigned int* flags = (unsigned int*)(ws + FLAG_OFF);

    // zero h[0..1] + flags each call (deterministic across graph replays)
    hipMemsetAsync(ws + H_OFF, 0, 524288 + 16384, stream);

    wprep_kernel<<<784, 256, 0, stream>>>(Wx, Wh, Wenc, wcat, wencf);
    enc_kernel<<<dim3(2048, 4), 256, 0, stream>>>(x, benc, wencf, enc);

    hipFuncSetAttribute(reinterpret_cast<const void*>(lstm_kernel),
                        hipFuncAttributeMaxDynamicSharedMemorySize, 90112);
    lstm_kernel<<<256, 256, 90112, stream>>>(enc, wcat, blstm, hbuf, flags);

    dec_kernel<<<256, 64, 0, stream>>>(hbuf, Wdec, bdec, (float*)d_out);
}

// Round 2
// 3298.727 us; speedup vs baseline: 5.4782x; 5.4782x over previous
//
#include <hip/hip_runtime.h>

// Problem dims
#define BATCH 256
#define TLEN  512
#define DIN   128
#define DFEAT 256
#define DLAT  512
#define G4    2048   // 4*DLAT
#define KCAT  768    // DFEAT + DLAT

typedef __bf16 bf16x8 __attribute__((ext_vector_type(8)));
typedef float f32x4 __attribute__((ext_vector_type(4)));

// ws layout (bytes)
#define WCAT_OFF   0u          // 768x2048 bf16 frag-linear: 3,145,728
#define WENC_OFF   3145728u    // 128x256  bf16 frag-linear: 65,536
#define ENC_OFF    3211264u    // enc bf16 [T][B][256]: 67,108,864
#define H_OFF      70320128u   // h dbuf bf16 [2][256][512]: 524,288
#define FLAG_OFF   70844416u   // 8 grp x 32 wg x 64B: 16,384

__device__ __forceinline__ float sigf(float x)  { return 1.0f / (1.0f + __expf(-x)); }
__device__ __forceinline__ float tanhfast(float x){ return 2.0f / (1.0f + __expf(-2.0f * x)) - 1.0f; }
__device__ __forceinline__ unsigned short bfb(float f) {
    __bf16 b = (__bf16)f;
    return __builtin_bit_cast(unsigned short, b);
}

// ---------------------------------------------------------------------------
// Weight prep: build bf16 fragment-linear copies of [W_x;W_h] (768x2048) and
// W_enc (128x256). Fragment chunk = 16B for one lane of one 16x16x32 B-frag:
// B[k = ks*32 + (l>>4)*8 + j][col], col = (l&15) within a 16-col Ntile.
// ---------------------------------------------------------------------------
__global__ __launch_bounds__(256) void wprep_kernel(const float* __restrict__ Wx,
                                                    const float* __restrict__ Wh,
                                                    const float* __restrict__ Wenc,
                                                    __bf16* __restrict__ wcat,
                                                    __bf16* __restrict__ wencf) {
    int cid = blockIdx.x * 256 + threadIdx.x;   // 200704 total
    float v[8];
    __bf16* dst;
    if (cid < 196608) {
        // Wcat: cid = ((widx*4 + nt)*24 + ks)*64 + l
        int widx = cid / 6144;
        int r1 = cid % 6144;
        int nt = r1 / 1536;
        int r2 = r1 % 1536;
        int ks = r2 >> 6, l = r2 & 63;
        int col = nt * 512 + widx * 16 + (l & 15);
        int kc = ks * 32 + (l >> 4) * 8;
#pragma unroll
        for (int j = 0; j < 8; ++j) {
            int kk = kc + j;
            v[j] = (kk < DFEAT) ? Wx[kk * G4 + col] : Wh[(kk - DFEAT) * G4 + col];
        }
        dst = wcat + (size_t)cid * 8;
    } else {
        // Wenc: c2 = ((ntg*4 + ks)*64 + l)
        int c2 = cid - 196608;   // [0, 4096)
        int ntg = c2 >> 8;
        int r = c2 & 255;
        int ks = r >> 6, l = r & 63;
        int col = ntg * 16 + (l & 15);
        int kc = ks * 32 + (l >> 4) * 8;
#pragma unroll
        for (int j = 0; j < 8; ++j) v[j] = Wenc[(kc + j) * DFEAT + col];
        dst = wencf + (size_t)c2 * 8;
    }
    bf16x8 o;
#pragma unroll
    for (int j = 0; j < 8; ++j) o[j] = (__bf16)v[j];
    *reinterpret_cast<bf16x8*>(dst) = o;
}

// ---------------------------------------------------------------------------
// Encoder: enc[t][b][f] = tanh(x[b][t][:] @ W_enc + b_enc), bf16 out.
// Block: 64 rows (rid = b*512+t) x 64 cols. 4 waves, wave = 1 Mtile x 4 Ntiles.
// ---------------------------------------------------------------------------
__global__ __launch_bounds__(256) void enc_kernel(const float* __restrict__ x,
                                                  const float* __restrict__ benc,
                                                  const __bf16* __restrict__ wencf,
                                                  __bf16* __restrict__ enc) {
    __shared__ uint4 afrag4[1024];   // 16 KB frag-linear A: [(m*4+ks)*64 + l]
    __bf16* afrag = reinterpret_cast<__bf16*>(afrag4);
    int tid = threadIdx.x;
    int lane = tid & 63, w = tid >> 6;
    int rid0 = blockIdx.x * 64;
    int ntg0 = blockIdx.y * 4;

    bf16x8 wr[4][4];
#pragma unroll
    for (int n = 0; n < 4; ++n)
#pragma unroll
        for (int ks = 0; ks < 4; ++ks)
            wr[n][ks] = *reinterpret_cast<const bf16x8*>(
                wencf + (size_t)(((ntg0 + n) * 4 + ks) * 64 + lane) * 8);
    float bias[4];
#pragma unroll
    for (int n = 0; n < 4; ++n) bias[n] = benc[(ntg0 + n) * 16 + (lane & 15)];

    // stage x tile (64 rows x 128 k) as bf16 frags
#pragma unroll
    for (int i = 0; i < 4; ++i) {
        int c = tid + 256 * i;          // [0,1024): row = c>>4, k8 = c&15
        int row = c >> 4, k8 = c & 15;
        const float* src = x + (size_t)(rid0 + row) * DIN + k8 * 8;
        float4 f0 = *reinterpret_cast<const float4*>(src);
        float4 f1 = *reinterpret_cast<const float4*>(src + 4);
        bf16x8 o;
        o[0] = (__bf16)f0.x; o[1] = (__bf16)f0.y; o[2] = (__bf16)f0.z; o[3] = (__bf16)f0.w;
        o[4] = (__bf16)f1.x; o[5] = (__bf16)f1.y; o[6] = (__bf16)f1.z; o[7] = (__bf16)f1.w;
        int l = (k8 & 3) * 16 + (row & 15);
        int a16 = ((row >> 4) * 4 + (k8 >> 2)) * 64 + l;
        *reinterpret_cast<bf16x8*>(afrag + (size_t)a16 * 8) = o;
    }
    __syncthreads();

    int m = w;
    f32x4 acc[4];
#pragma unroll
    for (int n = 0; n < 4; ++n) acc[n] = (f32x4){bias[n], bias[n], bias[n], bias[n]};
#pragma unroll
    for (int ks = 0; ks < 4; ++ks) {
        bf16x8 a = *reinterpret_cast<const bf16x8*>(afrag + (size_t)((m * 4 + ks) * 64 + lane) * 8);
#pragma unroll
        for (int n = 0; n < 4; ++n)
            acc[n] = __builtin_amdgcn_mfma_f32_16x16x32_bf16(a, wr[n][ks], acc[n], 0, 0, 0);
    }
#pragma unroll
    for (int n = 0; n < 4; ++n) {
        int colg = (ntg0 + n) * 16 + (lane & 15);
#pragma unroll
        for (int q = 0; q < 4; ++q) {
            int rid = rid0 + m * 16 + (lane >> 4) * 4 + q;
            int bb = rid >> 9, tt = rid & 511;
            float th = tanhfast(acc[n][q]);
            enc[(size_t)(tt * BATCH + bb) * DFEAT + colg] = (__bf16)th;
        }
    }
}

// ---------------------------------------------------------------------------
// Persistent LSTM. grid=256 (grp = bid&7 -> 32 batch rows; widx = bid>>3 ->
// 16 k-cols = 64 gate-cols). Weights in VGPRs (48 frags). A = [enc_t | h] in
// fragment-linear LDS.
//
// Inter-block exchange is FENCE-FREE: h and flags move through the LLC via
// relaxed agent-scope (sc1) atomics. __syncthreads() drains vmcnt(0) per wave
// before s_barrier, so all h stores are LLC-visible before tid0 publishes the
// flag. Pollers spin on relaxed loads (no buffer_inv) and read h with relaxed
// sc1 loads (always served by LLC -> never stale). No threadfence, no
// acquire fence, no L2 writeback/invalidate on the critical path.
// ---------------------------------------------------------------------------
__global__ __launch_bounds__(256, 1) void lstm_kernel(const __bf16* __restrict__ enc,
                                                      const __bf16* __restrict__ wcat,
                                                      const float* __restrict__ blstm,
                                                      __bf16* __restrict__ hbuf,
                                                      unsigned int* __restrict__ flags) {
    extern __shared__ char smem[];
    __bf16* afrag = reinterpret_cast<__bf16*>(smem);        // 49152 B
    float* zbuf = reinterpret_cast<float*>(smem + 49152);   // 8192 B: [4][32][16]

    int tid = threadIdx.x;
    int lane = tid & 63, w = tid >> 6;
    int m = w & 1, np = w >> 1;
    int grp = blockIdx.x & 7, widx = blockIdx.x >> 3;
    int b0 = grp * 32;

    // persistent weight frags
    bf16x8 wreg[2][24];
#pragma unroll
    for (int n2 = 0; n2 < 2; ++n2)
#pragma unroll
        for (int ks = 0; ks < 24; ++ks)
            wreg[n2][ks] = *reinterpret_cast<const bf16x8*>(
                wcat + (size_t)(((widx * 4 + np * 2 + n2) * 24 + ks) * 64 + lane) * 8);
    float bias[2];
#pragma unroll
    for (int n2 = 0; n2 < 2; ++n2)
        bias[n2] = blstm[(np * 2 + n2) * DLAT + widx * 16 + (lane & 15)];

    // cell state: thread owns cells 2*tid, 2*tid+1 of the wg's 32x16 slice
    int cell = 2 * tid;
    int crow = cell >> 4, ckk = cell & 15;
    float c0 = 0.f, c1 = 0.f;
    unsigned int* myflag = flags + (grp * 32 + widx) * 16;

#pragma unroll 1
    for (int t = 0; t < TLEN; ++t) {
        if (t > 0) {
            if (tid < 32) {
                const unsigned int* f = flags + (grp * 32 + tid) * 16;
                // relaxed sc1 poll: no cache invalidation, served by LLC
                while (__hip_atomic_load(f, __ATOMIC_RELAXED, __HIP_MEMORY_SCOPE_AGENT) <
                       (unsigned)t) {}
            }
            __syncthreads();
        }
        // stage A = [enc_t | h(t)] : 32 rows x 768 k, frag-linear
        const __bf16* hsrc = hbuf + (size_t)(t & 1) * (BATCH * DLAT);
#pragma unroll
        for (int i = 0; i < 12; ++i) {
            int c = tid + 256 * i;              // [0,3072)
            int mm = (c >= 1536) ? 1 : 0;
            int r = c - mm * 1536;
            int ks = r >> 6, l = r & 63;
            int row = mm * 16 + (l & 15);
            int k = (ks * 4 + (l >> 4)) * 8;
            uint4 d;
            if (k < DFEAT) {
                d = *reinterpret_cast<const uint4*>(
                    enc + (size_t)(t * BATCH + b0 + row) * DFEAT + k);
            } else {
                // h read: relaxed agent (sc1) 8B atomic loads -> always from LLC
                const unsigned long long* hp8 = reinterpret_cast<const unsigned long long*>(
                    hsrc + (size_t)(b0 + row) * DLAT + (k - DFEAT));
                unsigned long long lo =
                    __hip_atomic_load(hp8, __ATOMIC_RELAXED, __HIP_MEMORY_SCOPE_AGENT);
                unsigned long long hi =
                    __hip_atomic_load(hp8 + 1, __ATOMIC_RELAXED, __HIP_MEMORY_SCOPE_AGENT);
                d.x = (unsigned int)lo;
                d.y = (unsigned int)(lo >> 32);
                d.z = (unsigned int)hi;
                d.w = (unsigned int)(hi >> 32);
            }
            *reinterpret_cast<uint4*>(afrag + (size_t)c * 8) = d;
        }
        __syncthreads();

        // z = A @ Wslice (+bias)
        f32x4 acc[2];
        acc[0] = (f32x4){bias[0], bias[0], bias[0], bias[0]};
        acc[1] = (f32x4){bias[1], bias[1], bias[1], bias[1]};
#pragma unroll
        for (int ks = 0; ks < 24; ++ks) {
            bf16x8 a = *reinterpret_cast<const bf16x8*>(
                afrag + (size_t)((m * 24 + ks) * 64 + lane) * 8);
            acc[0] = __builtin_amdgcn_mfma_f32_16x16x32_bf16(a, wreg[0][ks], acc[0], 0, 0, 0);
            acc[1] = __builtin_amdgcn_mfma_f32_16x16x32_bf16(a, wreg[1][ks], acc[1], 0, 0, 0);
        }
        // z exchange: zbuf[g][rowInWg][kk]
#pragma unroll
        for (int n2 = 0; n2 < 2; ++n2) {
            int g = np * 2 + n2;
#pragma unroll
            for (int q = 0; q < 4; ++q) {
                int rr = m * 16 + (lane >> 4) * 4 + q;
                zbuf[g * 512 + rr * 16 + (lane & 15)] = acc[n2][q];
            }
        }
        __syncthreads();

        // gates + state update (2 cells per thread)
        float2 zi = *reinterpret_cast<float2*>(&zbuf[0 * 512 + cell]);
        float2 zf = *reinterpret_cast<float2*>(&zbuf[1 * 512 + cell]);
        float2 zg = *reinterpret_cast<float2*>(&zbuf[2 * 512 + cell]);
        float2 zo = *reinterpret_cast<float2*>(&zbuf[3 * 512 + cell]);
        float i0 = sigf(zi.x), f0 = sigf(zf.x), g0 = tanhfast(zg.x), o0 = sigf(zo.x);
        c0 = f0 * c0 + i0 * g0;
        float h0 = o0 * tanhfast(c0);
        float i1 = sigf(zi.y), f1 = sigf(zf.y), g1 = tanhfast(zg.y), o1 = sigf(zo.y);
        c1 = f1 * c1 + i1 * g1;
        float h1 = o1 * tanhfast(c1);

        unsigned int hp = (unsigned int)bfb(h0) | ((unsigned int)bfb(h1) << 16);
        unsigned int* hdst = reinterpret_cast<unsigned int*>(
            hbuf + (size_t)((t + 1) & 1) * (BATCH * DLAT) +
            (size_t)(b0 + crow) * DLAT + widx * 16 + ckk);
        // relaxed agent (sc1) store -> lands in LLC, visible to all XCDs
        __hip_atomic_store(hdst, hp, __ATOMIC_RELAXED, __HIP_MEMORY_SCOPE_AGENT);

        // __syncthreads drains vmcnt(0) per wave before s_barrier => all h
        // stores are LLC-visible before the flag below is published.
        __syncthreads();
        if (tid == 0)
            __hip_atomic_store(myflag, (unsigned int)(t + 1), __ATOMIC_RELAXED,
                               __HIP_MEMORY_SCOPE_AGENT);
    }
}

// ---------------------------------------------------------------------------
// Decoder: out[b] = h_last[b,:] @ W_dec + b_dec. h_last is hbuf[0] (T even).
// ---------------------------------------------------------------------------
__global__ __launch_bounds__(64) void dec_kernel(const __bf16* __restrict__ hbuf,
                                                 const float* __restrict__ wdec,
                                                 const float* __restrict__ bdec,
                                                 float* __restrict__ out) {
    int b = blockIdx.x, lane = threadIdx.x;
    uint4 d = *reinterpret_cast<const uint4*>(hbuf + (size_t)b * DLAT + lane * 8);
    const __bf16* hv = reinterpret_cast<const __bf16*>(&d);
    float4 w0 = *reinterpret_cast<const float4*>(wdec + lane * 8);
    float4 w1 = *reinterpret_cast<const float4*>(wdec + lane * 8 + 4);
    float s = (float)hv[0] * w0.x + (float)hv[1] * w0.y + (float)hv[2] * w0.z +
              (float)hv[3] * w0.w + (float)hv[4] * w1.x + (float)hv[5] * w1.y +
              (float)hv[6] * w1.z + (float)hv[7] * w1.w;
#pragma unroll
    for (int off = 32; off; off >>= 1) s += __shfl_xor(s, off);
    if (lane == 0) out[b] = s + bdec[0];
}

extern "C" void kernel_launch(void* const* d_in, const int* in_sizes, int n_in,
                              void* d_out, int out_size, void* d_ws, size_t ws_size,
                              hipStream_t stream) {
    (void)in_sizes; (void)n_in; (void)out_size; (void)ws_size;
    const float* x     = (const float*)d_in[0];
    const float* Wenc  = (const float*)d_in[1];
    const float* benc  = (const float*)d_in[2];
    const float* Wx    = (const float*)d_in[3];
    const float* Wh    = (const float*)d_in[4];
    const float* blstm = (const float*)d_in[5];
    const float* Wdec  = (const float*)d_in[6];
    const float* bdec  = (const float*)d_in[7];

    char* ws = (char*)d_ws;
    __bf16* wcat  = (__bf16*)(ws + WCAT_OFF);
    __bf16* wencf = (__bf16*)(ws + WENC_OFF);
    __bf16* enc   = (__bf16*)(ws + ENC_OFF);
    __bf16* hbuf  = (__bf16*)(ws + H_OFF);
    unsigned int* flags = (unsigned int*)(ws + FLAG_OFF);

    // zero h[0..1] + flags each call (deterministic across graph replays)
    hipMemsetAsync(ws + H_OFF, 0, 524288 + 16384, stream);

    wprep_kernel<<<784, 256, 0, stream>>>(Wx, Wh, Wenc, wcat, wencf);
    enc_kernel<<<dim3(2048, 4), 256, 0, stream>>>(x, benc, wencf, enc);

    hipFuncSetAttribute(reinterpret_cast<const void*>(lstm_kernel),
                        hipFuncAttributeMaxDynamicSharedMemorySize, 90112);
    lstm_kernel<<<256, 256, 90112, stream>>>(enc, wcat, blstm, hbuf, flags);

    dec_kernel<<<256, 64, 0, stream>>>(hbuf, Wdec, bdec, (float*)d_out);
}

// Round 5
// 1938.523 us; speedup vs baseline: 9.3221x; 1.7017x over previous
//
#include <hip/hip_runtime.h>

// Problem dims
#define BATCH 256
#define TLEN  512
#define DIN   128
#define DFEAT 256
#define DLAT  512
#define G4    2048   // 4*DLAT
#define KCAT  768    // DFEAT + DLAT

typedef __bf16 bf16x8 __attribute__((ext_vector_type(8)));
typedef float f32x4 __attribute__((ext_vector_type(4)));

// ws layout (bytes)
#define WCAT_OFF   0u          // 768x2048 bf16 frag-linear: 3,145,728
#define WENC_OFF   3145728u    // 128x256  bf16 frag-linear: 65,536
#define ENC_OFF    3211264u    // enc bf16 [T][B][256]: 67,108,864
#define H_OFF      70320128u   // h dbuf bf16 [2][256][512]: 524,288
#define FLAG_OFF   70844416u   // counters region: 16,384
// flags region (uint elements): group counter ctr[grp] at flags[grp*64]

__device__ __forceinline__ float sigf(float x)  { return 1.0f / (1.0f + __expf(-x)); }
__device__ __forceinline__ float tanhfast(float x){ return 2.0f / (1.0f + __expf(-2.0f * x)) - 1.0f; }
__device__ __forceinline__ unsigned short bfb(float f) {
    __bf16 b = (__bf16)f;
    return __builtin_bit_cast(unsigned short, b);
}

// ---------------------------------------------------------------------------
// Weight prep: bf16 fragment-linear copies of [W_x;W_h] (768x2048) and W_enc.
// Fragment chunk = 16B for one lane of one 16x16x32 B-frag:
// B[k = ks*32 + (l>>4)*8 + j][col], col = (l&15) within a 16-col Ntile.
// ---------------------------------------------------------------------------
__global__ __launch_bounds__(256) void wprep_kernel(const float* __restrict__ Wx,
                                                    const float* __restrict__ Wh,
                                                    const float* __restrict__ Wenc,
                                                    __bf16* __restrict__ wcat,
                                                    __bf16* __restrict__ wencf) {
    int cid = blockIdx.x * 256 + threadIdx.x;   // 200704 total
    float v[8];
    __bf16* dst;
    if (cid < 196608) {
        int widx = cid / 6144;
        int r1 = cid % 6144;
        int nt = r1 / 1536;
        int r2 = r1 % 1536;
        int ks = r2 >> 6, l = r2 & 63;
        int col = nt * 512 + widx * 16 + (l & 15);
        int kc = ks * 32 + (l >> 4) * 8;
#pragma unroll
        for (int j = 0; j < 8; ++j) {
            int kk = kc + j;
            v[j] = (kk < DFEAT) ? Wx[kk * G4 + col] : Wh[(kk - DFEAT) * G4 + col];
        }
        dst = wcat + (size_t)cid * 8;
    } else {
        int c2 = cid - 196608;   // [0, 4096)
        int ntg = c2 >> 8;
        int r = c2 & 255;
        int ks = r >> 6, l = r & 63;
        int col = ntg * 16 + (l & 15);
        int kc = ks * 32 + (l >> 4) * 8;
#pragma unroll
        for (int j = 0; j < 8; ++j) v[j] = Wenc[(kc + j) * DFEAT + col];
        dst = wencf + (size_t)c2 * 8;
    }
    bf16x8 o;
#pragma unroll
    for (int j = 0; j < 8; ++j) o[j] = (__bf16)v[j];
    *reinterpret_cast<bf16x8*>(dst) = o;
}

// ---------------------------------------------------------------------------
// Encoder: enc[t][b][f] = tanh(x[b][t][:] @ W_enc + b_enc), bf16 out.
// ---------------------------------------------------------------------------
__global__ __launch_bounds__(256) void enc_kernel(const float* __restrict__ x,
                                                  const float* __restrict__ benc,
                                                  const __bf16* __restrict__ wencf,
                                                  __bf16* __restrict__ enc) {
    __shared__ uint4 afrag4[1024];   // 16 KB frag-linear A
    __bf16* afrag = reinterpret_cast<__bf16*>(afrag4);
    int tid = threadIdx.x;
    int lane = tid & 63, w = tid >> 6;
    int rid0 = blockIdx.x * 64;
    int ntg0 = blockIdx.y * 4;

    bf16x8 wr[4][4];
#pragma unroll
    for (int n = 0; n < 4; ++n)
#pragma unroll
        for (int ks = 0; ks < 4; ++ks)
            wr[n][ks] = *reinterpret_cast<const bf16x8*>(
                wencf + (size_t)(((ntg0 + n) * 4 + ks) * 64 + lane) * 8);
    float bias[4];
#pragma unroll
    for (int n = 0; n < 4; ++n) bias[n] = benc[(ntg0 + n) * 16 + (lane & 15)];

#pragma unroll
    for (int i = 0; i < 4; ++i) {
        int c = tid + 256 * i;          // [0,1024): row = c>>4, k8 = c&15
        int row = c >> 4, k8 = c & 15;
        const float* src = x + (size_t)(rid0 + row) * DIN + k8 * 8;
        float4 f0 = *reinterpret_cast<const float4*>(src);
        float4 f1 = *reinterpret_cast<const float4*>(src + 4);
        bf16x8 o;
        o[0] = (__bf16)f0.x; o[1] = (__bf16)f0.y; o[2] = (__bf16)f0.z; o[3] = (__bf16)f0.w;
        o[4] = (__bf16)f1.x; o[5] = (__bf16)f1.y; o[6] = (__bf16)f1.z; o[7] = (__bf16)f1.w;
        int l = (k8 & 3) * 16 + (row & 15);
        int a16 = ((row >> 4) * 4 + (k8 >> 2)) * 64 + l;
        *reinterpret_cast<bf16x8*>(afrag + (size_t)a16 * 8) = o;
    }
    __syncthreads();

    int m = w;
    f32x4 acc[4];
#pragma unroll
    for (int n = 0; n < 4; ++n) acc[n] = (f32x4){bias[n], bias[n], bias[n], bias[n]};
#pragma unroll
    for (int ks = 0; ks < 4; ++ks) {
        bf16x8 a = *reinterpret_cast<const bf16x8*>(afrag + (size_t)((m * 4 + ks) * 64 + lane) * 8);
#pragma unroll
        for (int n = 0; n < 4; ++n)
            acc[n] = __builtin_amdgcn_mfma_f32_16x16x32_bf16(a, wr[n][ks], acc[n], 0, 0, 0);
    }
#pragma unroll
    for (int n = 0; n < 4; ++n) {
        int colg = (ntg0 + n) * 16 + (lane & 15);
#pragma unroll
        for (int q = 0; q < 4; ++q) {
            int rid = rid0 + m * 16 + (lane >> 4) * 4 + q;
            int bb = rid >> 9, tt = rid & 511;
            float th = tanhfast(acc[n][q]);
            enc[(size_t)(tt * BATCH + bb) * DFEAT + colg] = (__bf16)th;
        }
    }
}

// ---------------------------------------------------------------------------
// Persistent LSTM. grid=256; grp = bid&7 (32 batch rows), widx = bid>>3
// (16 h-cols => 64 gate-cols). Weights persistent in registers. All
// inter-block exchange via the LLC using relaxed agent-scope (sc1) accesses
// -- the round-2-proven protocol (no fences, no cache flush/invalidate).
//   release: per-group counting barrier; __syncthreads() drains each wave's
//            vmcnt(0) (so wave-0's sc1 h stores are LLC-visible), then tid0
//            atomicAdd(ctr).
//   acquire: tid0 polls ctr >= 32*t with relaxed agent loads, then barrier.
//   h data:  batched global_load_dwordx4 sc1 (LLC-coherent, 16B wide;
//            vector OUTPUT operands only -- vector inputs don't compile).
// Critical-path split: enc-part MFMAs (ks 0..7) run before the poll.
// ---------------------------------------------------------------------------
__global__ __launch_bounds__(256, 1) void lstm_kernel(const __bf16* __restrict__ enc,
                                                      const __bf16* __restrict__ wcat,
                                                      const float* __restrict__ blstm,
                                                      __bf16* __restrict__ hbuf,
                                                      unsigned int* __restrict__ flags) {
    extern __shared__ char smem[];
    __bf16* afrag = reinterpret_cast<__bf16*>(smem);                 // 49152 B
    float* zbuf = reinterpret_cast<float*>(smem + 49152);           // 8192 B
    unsigned int* hstage = reinterpret_cast<unsigned int*>(smem + 57344); // 1024 B

    int tid = threadIdx.x;
    int lane = tid & 63, w = tid >> 6;
    int m = w & 1, np = w >> 1;
    int grp = blockIdx.x & 7, widx = blockIdx.x >> 3;
    int b0 = grp * 32;
    unsigned int* ctr = &flags[grp * 64];

    // persistent weight frags (column slice widx: h-cols widx*16..+16, 4 gates)
    bf16x8 wreg[2][24];
#pragma unroll
    for (int n2 = 0; n2 < 2; ++n2)
#pragma unroll
        for (int ks = 0; ks < 24; ++ks)
            wreg[n2][ks] = *reinterpret_cast<const bf16x8*>(
                wcat + (size_t)(((widx * 4 + np * 2 + n2) * 24 + ks) * 64 + lane) * 8);
    float bias[2];
#pragma unroll
    for (int n2 = 0; n2 < 2; ++n2)
        bias[n2] = blstm[(np * 2 + n2) * DLAT + widx * 16 + (lane & 15)];

    // cell state: thread owns cells 2*tid, 2*tid+1 of the wg's 32x16 slice
    int cell = 2 * tid;
    float c0 = 0.f, c1 = 0.f;

#pragma unroll 1
    for (int t = 0; t < TLEN; ++t) {
        // (1) stage enc_t chunks (h-independent): chunk ids iv in {0,1,6,7}
#pragma unroll
        for (int ii = 0; ii < 4; ++ii) {
            const int iv = (ii < 2) ? ii : ii + 4;
            int c = tid + 256 * iv;
            int mm = (c >= 1536) ? 1 : 0;
            int r = c - mm * 1536;
            int ks = r >> 6, l = r & 63;
            int row = mm * 16 + (l & 15);
            int k = (ks * 4 + (l >> 4)) * 8;
            uint4 d = *reinterpret_cast<const uint4*>(
                enc + (size_t)(t * BATCH + b0 + row) * DFEAT + k);
            *reinterpret_cast<uint4*>(afrag + (size_t)c * 8) = d;
        }
        __syncthreads();

        // (2) enc-part MFMAs (ks 0..7) -- h-independent, runs before the poll
        f32x4 acc[2];
        acc[0] = (f32x4){bias[0], bias[0], bias[0], bias[0]};
        acc[1] = (f32x4){bias[1], bias[1], bias[1], bias[1]};
#pragma unroll
        for (int ks = 0; ks < 8; ++ks) {
            bf16x8 a = *reinterpret_cast<const bf16x8*>(
                afrag + (size_t)((m * 24 + ks) * 64 + lane) * 8);
            acc[0] = __builtin_amdgcn_mfma_f32_16x16x32_bf16(a, wreg[0][ks], acc[0], 0, 0, 0);
            acc[1] = __builtin_amdgcn_mfma_f32_16x16x32_bf16(a, wreg[1][ks], acc[1], 0, 0, 0);
        }

        if (t > 0) {
            // (3) acquire: counting barrier, ctr >= 32*t  (proven r2 protocol)
            if (tid == 0) {
                unsigned tgt = 32u * (unsigned)t;
                while (__hip_atomic_load(ctr, __ATOMIC_RELAXED,
                                         __HIP_MEMORY_SCOPE_AGENT) < tgt) {}
            }
            __syncthreads();

            // (4) stage h(t) slice: batched 16B sc1 loads (LLC-coherent)
            {
                const __bf16* hsrc = hbuf + (size_t)(t & 1) * (BATCH * DLAT);
                const __bf16* src[8];
                int cdst[8];
#pragma unroll
                for (int ii = 0; ii < 8; ++ii) {
                    const int iv = (ii < 4) ? ii + 2 : ii + 4;
                    int c = tid + 256 * iv;
                    int mm = (c >= 1536) ? 1 : 0;
                    int r = c - mm * 1536;
                    int ks = r >> 6, l = r & 63;
                    int row = mm * 16 + (l & 15);
                    int k = (ks * 4 + (l >> 4)) * 8;
                    src[ii] = hsrc + (size_t)(b0 + row) * DLAT + (k - DFEAT);
                    cdst[ii] = c;
                }
                uint4 d0, d1, d2, d3, d4, d5, d6, d7;
                asm volatile(
                    "global_load_dwordx4 %0, %8, off sc1\n\t"
                    "global_load_dwordx4 %1, %9, off sc1\n\t"
                    "global_load_dwordx4 %2, %10, off sc1\n\t"
                    "global_load_dwordx4 %3, %11, off sc1\n\t"
                    "global_load_dwordx4 %4, %12, off sc1\n\t"
                    "global_load_dwordx4 %5, %13, off sc1\n\t"
                    "global_load_dwordx4 %6, %14, off sc1\n\t"
                    "global_load_dwordx4 %7, %15, off sc1\n\t"
                    "s_waitcnt vmcnt(0)"
                    : "=&v"(d0), "=&v"(d1), "=&v"(d2), "=&v"(d3),
                      "=&v"(d4), "=&v"(d5), "=&v"(d6), "=&v"(d7)
                    : "v"(src[0]), "v"(src[1]), "v"(src[2]), "v"(src[3]),
                      "v"(src[4]), "v"(src[5]), "v"(src[6]), "v"(src[7])
                    : "memory");
                *reinterpret_cast<uint4*>(afrag + (size_t)cdst[0] * 8) = d0;
                *reinterpret_cast<uint4*>(afrag + (size_t)cdst[1] * 8) = d1;
                *reinterpret_cast<uint4*>(afrag + (size_t)cdst[2] * 8) = d2;
                *reinterpret_cast<uint4*>(afrag + (size_t)cdst[3] * 8) = d3;
                *reinterpret_cast<uint4*>(afrag + (size_t)cdst[4] * 8) = d4;
                *reinterpret_cast<uint4*>(afrag + (size_t)cdst[5] * 8) = d5;
                *reinterpret_cast<uint4*>(afrag + (size_t)cdst[6] * 8) = d6;
                *reinterpret_cast<uint4*>(afrag + (size_t)cdst[7] * 8) = d7;
            }
            __syncthreads();

            // (5) h-part MFMAs (ks 8..23)
#pragma unroll
            for (int ks = 8; ks < 24; ++ks) {
                bf16x8 a = *reinterpret_cast<const bf16x8*>(
                    afrag + (size_t)((m * 24 + ks) * 64 + lane) * 8);
                acc[0] = __builtin_amdgcn_mfma_f32_16x16x32_bf16(a, wreg[0][ks], acc[0], 0, 0, 0);
                acc[1] = __builtin_amdgcn_mfma_f32_16x16x32_bf16(a, wreg[1][ks], acc[1], 0, 0, 0);
            }
        }

        // (6) z exchange via LDS: zbuf[g][rowInWg][kk]
#pragma unroll
        for (int n2 = 0; n2 < 2; ++n2) {
            int g = np * 2 + n2;
#pragma unroll
            for (int q = 0; q < 4; ++q) {
                int rr = m * 16 + (lane >> 4) * 4 + q;
                zbuf[g * 512 + rr * 16 + (lane & 15)] = acc[n2][q];
            }
        }
        __syncthreads();

        // (7) gates + state update (2 cells per thread), h -> LDS repack
        float2 zi = *reinterpret_cast<float2*>(&zbuf[0 * 512 + cell]);
        float2 zf = *reinterpret_cast<float2*>(&zbuf[1 * 512 + cell]);
        float2 zg = *reinterpret_cast<float2*>(&zbuf[2 * 512 + cell]);
        float2 zo = *reinterpret_cast<float2*>(&zbuf[3 * 512 + cell]);
        float i0 = sigf(zi.x), f0 = sigf(zf.x), g0 = tanhfast(zg.x), o0 = sigf(zo.x);
        c0 = f0 * c0 + i0 * g0;
        float h0 = o0 * tanhfast(c0);
        float i1 = sigf(zi.y), f1 = sigf(zf.y), g1 = tanhfast(zg.y), o1 = sigf(zo.y);
        c1 = f1 * c1 + i1 * g1;
        float h1 = o1 * tanhfast(c1);
        hstage[tid] = (unsigned int)bfb(h0) | ((unsigned int)bfb(h1) << 16);
        __syncthreads();

        // (8) h store: wave 0 only, 128 x 8B relaxed-agent (sc1) stores
        if (tid < 64) {
            unsigned long long v0 =
                *reinterpret_cast<unsigned long long*>(&hstage[tid * 4]);
            unsigned long long v1 =
                *reinterpret_cast<unsigned long long*>(&hstage[tid * 4 + 2]);
            unsigned long long* dst8 = reinterpret_cast<unsigned long long*>(
                hbuf + (size_t)((t + 1) & 1) * (BATCH * DLAT) +
                (size_t)(b0 + (tid >> 1)) * DLAT + widx * 16 + (tid & 1) * 8);
            __hip_atomic_store(dst8, v0, __ATOMIC_RELAXED, __HIP_MEMORY_SCOPE_AGENT);
            __hip_atomic_store(dst8 + 1, v1, __ATOMIC_RELAXED, __HIP_MEMORY_SCOPE_AGENT);
        }
        // (9) release: __syncthreads drains vmcnt(0) per wave -> stores are
        // LLC-visible; then publish one increment.
        __syncthreads();
        if (tid == 0)
            atomicAdd(ctr, 1u);   // device(agent)-scope by default -> LLC
    }
}

// ---------------------------------------------------------------------------
// Decoder: out[b] = h_last[b,:] @ W_dec + b_dec. h_last is hbuf[0] (T even).
// ---------------------------------------------------------------------------
__global__ __launch_bounds__(64) void dec_kernel(const __bf16* __restrict__ hbuf,
                                                 const float* __restrict__ wdec,
                                                 const float* __restrict__ bdec,
                                                 float* __restrict__ out) {
    int b = blockIdx.x, lane = threadIdx.x;
    uint4 d = *reinterpret_cast<const uint4*>(hbuf + (size_t)b * DLAT + lane * 8);
    const __bf16* hv = reinterpret_cast<const __bf16*>(&d);
    float4 w0 = *reinterpret_cast<const float4*>(wdec + lane * 8);
    float4 w1 = *reinterpret_cast<const float4*>(wdec + lane * 8 + 4);
    float s = (float)hv[0] * w0.x + (float)hv[1] * w0.y + (float)hv[2] * w0.z +
              (float)hv[3] * w0.w + (float)hv[4] * w1.x + (float)hv[5] * w1.y +
              (float)hv[6] * w1.z + (float)hv[7] * w1.w;
#pragma unroll
    for (int off = 32; off; off >>= 1) s += __shfl_xor(s, off);
    if (lane == 0) out[b] = s + bdec[0];
}

extern "C" void kernel_launch(void* const* d_in, const int* in_sizes, int n_in,
                              void* d_out, int out_size, void* d_ws, size_t ws_size,
                              hipStream_t stream) {
    (void)in_sizes; (void)n_in; (void)out_size; (void)ws_size;
    const float* x     = (const float*)d_in[0];
    const float* Wenc  = (const float*)d_in[1];
    const float* benc  = (const float*)d_in[2];
    const float* Wx    = (const float*)d_in[3];
    const float* Wh    = (const float*)d_in[4];
    const float* blstm = (const float*)d_in[5];
    const float* Wdec  = (const float*)d_in[6];
    const float* bdec  = (const float*)d_in[7];

    char* ws = (char*)d_ws;
    __bf16* wcat  = (__bf16*)(ws + WCAT_OFF);
    __bf16* wencf = (__bf16*)(ws + WENC_OFF);
    __bf16* enc   = (__bf16*)(ws + ENC_OFF);
    __bf16* hbuf  = (__bf16*)(ws + H_OFF);
    unsigned int* flags = (unsigned int*)(ws + FLAG_OFF);

    // zero the barrier counters each call (deterministic across graph replays)
    (void)hipMemsetAsync(ws + FLAG_OFF, 0, 16384, stream);

    wprep_kernel<<<784, 256, 0, stream>>>(Wx, Wh, Wenc, wcat, wencf);
    enc_kernel<<<dim3(2048, 4), 256, 0, stream>>>(x, benc, wencf, enc);

    (void)hipFuncSetAttribute(reinterpret_cast<const void*>(lstm_kernel),
                              hipFuncAttributeMaxDynamicSharedMemorySize, 90112);
    lstm_kernel<<<256, 256, 90112, stream>>>(enc, wcat, blstm, hbuf, flags);

    dec_kernel<<<256, 64, 0, stream>>>(hbuf, Wdec, bdec, (float*)d_out);
}

// Round 6
// 1454.504 us; speedup vs baseline: 12.4242x; 1.3328x over previous
//
#include <hip/hip_runtime.h>

// Problem dims
#define BATCH 256
#define TLEN  512
#define DIN   128
#define DFEAT 256
#define DLAT  512
#define G4    2048   // 4*DLAT
#define KCAT  768    // DFEAT + DLAT

typedef __bf16 bf16x8 __attribute__((ext_vector_type(8)));
typedef float f32x4 __attribute__((ext_vector_type(4)));

// ws layout (bytes)
#define WCAT_OFF   0u          // 768x2048 bf16 frag-linear: 3,145,728
#define WENC_OFF   3145728u    // 128x256  bf16 frag-linear: 65,536
#define ENC_OFF    3211264u    // enc bf16 [T][B][256]: 67,108,864
#define H_OFF      70320128u   // h dbuf bf16 [2][256][512]: 524,288
#define FLAG_OFF   70844416u   // flags: (grp*16+widx)*16 uints (64B apart): 16,384

__device__ __forceinline__ float sigf(float x)  { return 1.0f / (1.0f + __expf(-x)); }
__device__ __forceinline__ float tanhfast(float x){ return 2.0f / (1.0f + __expf(-2.0f * x)) - 1.0f; }
__device__ __forceinline__ unsigned short bfb(float f) {
    __bf16 b = (__bf16)f;
    return __builtin_bit_cast(unsigned short, b);
}

// ---------------------------------------------------------------------------
// Weight prep: bf16 fragment-linear copies of [W_x;W_h] (768x2048) and W_enc.
// wcat layout (16-group geometry): chunk cid = (((widx*8 + np*2 + nt2)*24
// + ks)*64 + l), holding B[k = ks*32+(l>>4)*8 .. +8][col], with
// col = np*512 + widx*32 + nt2*16 + (l&15).  (widx 0..15, np = gate 0..3)
// ---------------------------------------------------------------------------
__global__ __launch_bounds__(256) void wprep_kernel(const float* __restrict__ Wx,
                                                    const float* __restrict__ Wh,
                                                    const float* __restrict__ Wenc,
                                                    __bf16* __restrict__ wcat,
                                                    __bf16* __restrict__ wencf) {
    int cid = blockIdx.x * 256 + threadIdx.x;   // 200704 total
    float v[8];
    __bf16* dst;
    if (cid < 196608) {
        int widx = cid / 12288;      // 16 wgs
        int r1 = cid % 12288;
        int nn = r1 / 1536;          // np*2 + nt2, 0..7
        int r2 = r1 % 1536;
        int ks = r2 >> 6, l = r2 & 63;
        int col = (nn >> 1) * 512 + widx * 32 + (nn & 1) * 16 + (l & 15);
        int kc = ks * 32 + (l >> 4) * 8;
#pragma unroll
        for (int j = 0; j < 8; ++j) {
            int kk = kc + j;
            v[j] = (kk < DFEAT) ? Wx[kk * G4 + col] : Wh[(kk - DFEAT) * G4 + col];
        }
        dst = wcat + (size_t)cid * 8;
    } else {
        int c2 = cid - 196608;   // [0, 4096)
        int ntg = c2 >> 8;
        int r = c2 & 255;
        int ks = r >> 6, l = r & 63;
        int col = ntg * 16 + (l & 15);
        int kc = ks * 32 + (l >> 4) * 8;
#pragma unroll
        for (int j = 0; j < 8; ++j) v[j] = Wenc[(kc + j) * DFEAT + col];
        dst = wencf + (size_t)c2 * 8;
    }
    bf16x8 o;
#pragma unroll
    for (int j = 0; j < 8; ++j) o[j] = (__bf16)v[j];
    *reinterpret_cast<bf16x8*>(dst) = o;
}

// ---------------------------------------------------------------------------
// Encoder: enc[t][b][f] = tanh(x[b][t][:] @ W_enc + b_enc), bf16 out.
// ---------------------------------------------------------------------------
__global__ __launch_bounds__(256) void enc_kernel(const float* __restrict__ x,
                                                  const float* __restrict__ benc,
                                                  const __bf16* __restrict__ wencf,
                                                  __bf16* __restrict__ enc) {
    __shared__ uint4 afrag4[1024];   // 16 KB frag-linear A
    __bf16* afrag = reinterpret_cast<__bf16*>(afrag4);
    int tid = threadIdx.x;
    int lane = tid & 63, w = tid >> 6;
    int rid0 = blockIdx.x * 64;
    int ntg0 = blockIdx.y * 4;

    bf16x8 wr[4][4];
#pragma unroll
    for (int n = 0; n < 4; ++n)
#pragma unroll
        for (int ks = 0; ks < 4; ++ks)
            wr[n][ks] = *reinterpret_cast<const bf16x8*>(
                wencf + (size_t)(((ntg0 + n) * 4 + ks) * 64 + lane) * 8);
    float bias[4];
#pragma unroll
    for (int n = 0; n < 4; ++n) bias[n] = benc[(ntg0 + n) * 16 + (lane & 15)];

#pragma unroll
    for (int i = 0; i < 4; ++i) {
        int c = tid + 256 * i;          // [0,1024): row = c>>4, k8 = c&15
        int row = c >> 4, k8 = c & 15;
        const float* src = x + (size_t)(rid0 + row) * DIN + k8 * 8;
        float4 f0 = *reinterpret_cast<const float4*>(src);
        float4 f1 = *reinterpret_cast<const float4*>(src + 4);
        bf16x8 o;
        o[0] = (__bf16)f0.x; o[1] = (__bf16)f0.y; o[2] = (__bf16)f0.z; o[3] = (__bf16)f0.w;
        o[4] = (__bf16)f1.x; o[5] = (__bf16)f1.y; o[6] = (__bf16)f1.z; o[7] = (__bf16)f1.w;
        int l = (k8 & 3) * 16 + (row & 15);
        int a16 = ((row >> 4) * 4 + (k8 >> 2)) * 64 + l;
        *reinterpret_cast<bf16x8*>(afrag + (size_t)a16 * 8) = o;
    }
    __syncthreads();

    int m = w;
    f32x4 acc[4];
#pragma unroll
    for (int n = 0; n < 4; ++n) acc[n] = (f32x4){bias[n], bias[n], bias[n], bias[n]};
#pragma unroll
    for (int ks = 0; ks < 4; ++ks) {
        bf16x8 a = *reinterpret_cast<const bf16x8*>(afrag + (size_t)((m * 4 + ks) * 64 + lane) * 8);
#pragma unroll
        for (int n = 0; n < 4; ++n)
            acc[n] = __builtin_amdgcn_mfma_f32_16x16x32_bf16(a, wr[n][ks], acc[n], 0, 0, 0);
    }
#pragma unroll
    for (int n = 0; n < 4; ++n) {
        int colg = (ntg0 + n) * 16 + (lane & 15);
#pragma unroll
        for (int q = 0; q < 4; ++q) {
            int rid = rid0 + m * 16 + (lane >> 4) * 4 + q;
            int bb = rid >> 9, tt = rid & 511;
            float th = tanhfast(acc[n][q]);
            enc[(size_t)(tt * BATCH + bb) * DFEAT + colg] = (__bf16)th;
        }
    }
}

// ---------------------------------------------------------------------------
// Persistent LSTM, 16 groups x 16 wgs.
//   grp = bid&15 -> 16 batch rows (b0 = grp*16); widx = bid>>4 -> 32 h-cols
//   (128 gate-cols). Wave np = gate np (i,f,g,o), 2 Ntiles each, 24 ks.
// Exchange protocol (r2/r5-proven, relaxed agent / sc1 via LLC, no fences):
//   release: per-thread 4B relaxed-agent h stores; __syncthreads() drains
//            each wave's vmcnt(0) -> LLC-visible; tid0 stores own flag = t+1.
//   acquire: wave 0 loads the group's 16 flags (one per lane&15, relaxed
//            agent) until __all(v >= t); then barrier; batched sc1 h loads.
// No same-address atomics anywhere (the r5 counting barrier serialized 32
// atomicAdds at one LLC line). enc-part MFMAs (ks 0..7) run before the poll.
// ---------------------------------------------------------------------------
__global__ __launch_bounds__(256, 1) void lstm_kernel(const __bf16* __restrict__ enc,
                                                      const __bf16* __restrict__ wcat,
                                                      const float* __restrict__ blstm,
                                                      __bf16* __restrict__ hbuf,
                                                      unsigned int* __restrict__ flags) {
    extern __shared__ char smem[];
    __bf16* afrag = reinterpret_cast<__bf16*>(smem);       // 24576 B: 1536 chunks
    float* zbuf = reinterpret_cast<float*>(smem + 24576);  // 8192 B: [4][16][32]

    int tid = threadIdx.x;
    int lane = tid & 63, np = tid >> 6;     // np = wave = gate
    int grp = blockIdx.x & 15, widx = blockIdx.x >> 4;
    int b0 = grp * 16;
    unsigned int* myflag = &flags[(grp * 16 + widx) * 16];

    // persistent weight frags: wave np holds gate np, Ntiles nt2 in {0,1}
    bf16x8 wreg[2][24];
#pragma unroll
    for (int nt2 = 0; nt2 < 2; ++nt2)
#pragma unroll
        for (int ks = 0; ks < 24; ++ks)
            wreg[nt2][ks] = *reinterpret_cast<const bf16x8*>(
                wcat + (size_t)((((widx * 8 + np * 2 + nt2) * 24) + ks) * 64 + lane) * 8);
    float bias[2];
#pragma unroll
    for (int nt2 = 0; nt2 < 2; ++nt2)
        bias[nt2] = blstm[np * 512 + widx * 32 + nt2 * 16 + (lane & 15)];

    // cell state: thread owns cells 2*tid, 2*tid+1 of the wg's 16x32 slice
    int cell = 2 * tid;
    int crow = cell >> 5, ccol = cell & 31;
    float c0 = 0.f, c1 = 0.f;

#pragma unroll 1
    for (int t = 0; t < TLEN; ++t) {
        // (1) stage enc_t chunks (ks 0..7): c in [0,512), 2 per thread
#pragma unroll
        for (int i = 0; i < 2; ++i) {
            int c = tid + 256 * i;
            int ks = c >> 6, l = c & 63;
            int row = l & 15;
            int k = ks * 32 + (l >> 4) * 8;
            uint4 d = *reinterpret_cast<const uint4*>(
                enc + (size_t)(t * BATCH + b0 + row) * DFEAT + k);
            *reinterpret_cast<uint4*>(afrag + (size_t)c * 8) = d;
        }
        __syncthreads();

        // (2) enc-part MFMAs (ks 0..7) -- h-independent, before the poll
        f32x4 acc[2];
        acc[0] = (f32x4){bias[0], bias[0], bias[0], bias[0]};
        acc[1] = (f32x4){bias[1], bias[1], bias[1], bias[1]};
#pragma unroll
        for (int ks = 0; ks < 8; ++ks) {
            bf16x8 a = *reinterpret_cast<const bf16x8*>(
                afrag + (size_t)((ks * 64 + lane) * 8));
            acc[0] = __builtin_amdgcn_mfma_f32_16x16x32_bf16(a, wreg[0][ks], acc[0], 0, 0, 0);
            acc[1] = __builtin_amdgcn_mfma_f32_16x16x32_bf16(a, wreg[1][ks], acc[1], 0, 0, 0);
        }

        if (t > 0) {
            // (3) acquire: wave 0 polls the group's 16 flags (no atomics)
            if (tid < 64) {
                const unsigned int* f = &flags[(grp * 16 + (lane & 15)) * 16];
                unsigned v;
                do {
                    v = __hip_atomic_load(f, __ATOMIC_RELAXED, __HIP_MEMORY_SCOPE_AGENT);
                } while (!__all((int)(v >= (unsigned)t)));
            }
            __syncthreads();

            // (4) stage h(t) slice (ks 8..23): c in [512,1536), 4 per thread,
            //     batched 16B sc1 loads (vector OUTPUTS only in asm)
            {
                const __bf16* hsrc = hbuf + (size_t)(t & 1) * (BATCH * DLAT);
                const __bf16* src[4];
                int cdst[4];
#pragma unroll
                for (int ii = 0; ii < 4; ++ii) {
                    int c = tid + 256 * (ii + 2);
                    int ks = c >> 6, l = c & 63;
                    int row = l & 15;
                    int kh = ks * 32 + (l >> 4) * 8 - DFEAT;
                    src[ii] = hsrc + (size_t)(b0 + row) * DLAT + kh;
                    cdst[ii] = c;
                }
                uint4 d0, d1, d2, d3;
                asm volatile(
                    "global_load_dwordx4 %0, %4, off sc1\n\t"
                    "global_load_dwordx4 %1, %5, off sc1\n\t"
                    "global_load_dwordx4 %2, %6, off sc1\n\t"
                    "global_load_dwordx4 %3, %7, off sc1\n\t"
                    "s_waitcnt vmcnt(0)"
                    : "=&v"(d0), "=&v"(d1), "=&v"(d2), "=&v"(d3)
                    : "v"(src[0]), "v"(src[1]), "v"(src[2]), "v"(src[3])
                    : "memory");
                *reinterpret_cast<uint4*>(afrag + (size_t)cdst[0] * 8) = d0;
                *reinterpret_cast<uint4*>(afrag + (size_t)cdst[1] * 8) = d1;
                *reinterpret_cast<uint4*>(afrag + (size_t)cdst[2] * 8) = d2;
                *reinterpret_cast<uint4*>(afrag + (size_t)cdst[3] * 8) = d3;
            }
            __syncthreads();

            // (5) h-part MFMAs (ks 8..23)
#pragma unroll
            for (int ks = 8; ks < 24; ++ks) {
                bf16x8 a = *reinterpret_cast<const bf16x8*>(
                    afrag + (size_t)((ks * 64 + lane) * 8));
                acc[0] = __builtin_amdgcn_mfma_f32_16x16x32_bf16(a, wreg[0][ks], acc[0], 0, 0, 0);
                acc[1] = __builtin_amdgcn_mfma_f32_16x16x32_bf16(a, wreg[1][ks], acc[1], 0, 0, 0);
            }
        }

        // (6) z exchange via LDS: zbuf[gate][row 0..15][col 0..31]
#pragma unroll
        for (int nt2 = 0; nt2 < 2; ++nt2) {
#pragma unroll
            for (int q = 0; q < 4; ++q) {
                int rr = (lane >> 4) * 4 + q;
                zbuf[np * 512 + rr * 32 + nt2 * 16 + (lane & 15)] = acc[nt2][q];
            }
        }
        __syncthreads();

        // (7) gates + state update (2 adjacent cells per thread) + direct store
        float2 zi = *reinterpret_cast<float2*>(&zbuf[0 * 512 + crow * 32 + ccol]);
        float2 zf = *reinterpret_cast<float2*>(&zbuf[1 * 512 + crow * 32 + ccol]);
        float2 zg = *reinterpret_cast<float2*>(&zbuf[2 * 512 + crow * 32 + ccol]);
        float2 zo = *reinterpret_cast<float2*>(&zbuf[3 * 512 + crow * 32 + ccol]);
        float i0 = sigf(zi.x), f0 = sigf(zf.x), g0 = tanhfast(zg.x), o0 = sigf(zo.x);
        c0 = f0 * c0 + i0 * g0;
        float h0 = o0 * tanhfast(c0);
        float i1 = sigf(zi.y), f1 = sigf(zf.y), g1 = tanhfast(zg.y), o1 = sigf(zo.y);
        c1 = f1 * c1 + i1 * g1;
        float h1 = o1 * tanhfast(c1);

        unsigned int hp = (unsigned int)bfb(h0) | ((unsigned int)bfb(h1) << 16);
        unsigned int* hdst = reinterpret_cast<unsigned int*>(
            hbuf + (size_t)((t + 1) & 1) * (BATCH * DLAT) +
            (size_t)(b0 + crow) * DLAT + widx * 32 + ccol);
        __hip_atomic_store(hdst, hp, __ATOMIC_RELAXED, __HIP_MEMORY_SCOPE_AGENT);

        // (8) release: __syncthreads drains each wave's vmcnt(0) -> stores
        // LLC-visible; then publish own flag (independent line per wg).
        __syncthreads();
        if (tid == 0)
            __hip_atomic_store(myflag, (unsigned int)(t + 1), __ATOMIC_RELAXED,
                               __HIP_MEMORY_SCOPE_AGENT);
    }
}

// ---------------------------------------------------------------------------
// Decoder: out[b] = h_last[b,:] @ W_dec + b_dec. h_last is hbuf[0] (T even).
// ---------------------------------------------------------------------------
__global__ __launch_bounds__(64) void dec_kernel(const __bf16* __restrict__ hbuf,
                                                 const float* __restrict__ wdec,
                                                 const float* __restrict__ bdec,
                                                 float* __restrict__ out) {
    int b = blockIdx.x, lane = threadIdx.x;
    uint4 d = *reinterpret_cast<const uint4*>(hbuf + (size_t)b * DLAT + lane * 8);
    const __bf16* hv = reinterpret_cast<const __bf16*>(&d);
    float4 w0 = *reinterpret_cast<const float4*>(wdec + lane * 8);
    float4 w1 = *reinterpret_cast<const float4*>(wdec + lane * 8 + 4);
    float s = (float)hv[0] * w0.x + (float)hv[1] * w0.y + (float)hv[2] * w0.z +
              (float)hv[3] * w0.w + (float)hv[4] * w1.x + (float)hv[5] * w1.y +
              (float)hv[6] * w1.z + (float)hv[7] * w1.w;
#pragma unroll
    for (int off = 32; off; off >>= 1) s += __shfl_xor(s, off);
    if (lane == 0) out[b] = s + bdec[0];
}

extern "C" void kernel_launch(void* const* d_in, const int* in_sizes, int n_in,
                              void* d_out, int out_size, void* d_ws, size_t ws_size,
                              hipStream_t stream) {
    (void)in_sizes; (void)n_in; (void)out_size; (void)ws_size;
    const float* x     = (const float*)d_in[0];
    const float* Wenc  = (const float*)d_in[1];
    const float* benc  = (const float*)d_in[2];
    const float* Wx    = (const float*)d_in[3];
    const float* Wh    = (const float*)d_in[4];
    const float* blstm = (const float*)d_in[5];
    const float* Wdec  = (const float*)d_in[6];
    const float* bdec  = (const float*)d_in[7];

    char* ws = (char*)d_ws;
    __bf16* wcat  = (__bf16*)(ws + WCAT_OFF);
    __bf16* wencf = (__bf16*)(ws + WENC_OFF);
    __bf16* enc   = (__bf16*)(ws + ENC_OFF);
    __bf16* hbuf  = (__bf16*)(ws + H_OFF);
    unsigned int* flags = (unsigned int*)(ws + FLAG_OFF);

    // zero the per-wg flags each call (deterministic across graph replays)
    (void)hipMemsetAsync(ws + FLAG_OFF, 0, 16384, stream);

    wprep_kernel<<<784, 256, 0, stream>>>(Wx, Wh, Wenc, wcat, wencf);
    enc_kernel<<<dim3(2048, 4), 256, 0, stream>>>(x, benc, wencf, enc);

    // 90 KB dynamic LDS forces 1 block/CU (exclusive CU per wg; 256 blocks
    // on 256 CUs). Kernel uses only 32 KB of it.
    (void)hipFuncSetAttribute(reinterpret_cast<const void*>(lstm_kernel),
                              hipFuncAttributeMaxDynamicSharedMemorySize, 90112);
    lstm_kernel<<<256, 256, 90112, stream>>>(enc, wcat, blstm, hbuf, flags);

    dec_kernel<<<256, 64, 0, stream>>>(hbuf, Wdec, bdec, (float*)d_out);
}